// Round 8
// baseline (229.845 us; speedup 1.0000x reference)
//
#include <hip/hip_runtime.h>
#include <hip/hip_bf16.h>
#include <math.h>

#define T_LEN 20000
#define HID 150

typedef __attribute__((ext_vector_type(8))) __bf16 bf16x8;
typedef __attribute__((ext_vector_type(4))) float f32x4;

__device__ __forceinline__ short f2bf(float f) {
    unsigned u = __float_as_uint(f);
    u = (u + 0x7fff + ((u >> 16) & 1)) >> 16;
    return (short)u;
}

__device__ __forceinline__ unsigned pk2(float a, float b) {
    __hip_bfloat162 h = __float22bfloat162_rn(make_float2(a, b));
    return *(unsigned*)&h;
}

__device__ __forceinline__ bf16x8 cvt8(float4 a, float4 b) {
    union { unsigned u[4]; bf16x8 v; } r;
    r.u[0] = pk2(a.x, a.y);
    r.u[1] = pk2(a.z, a.w);
    r.u[2] = pk2(b.x, b.y);
    r.u[3] = pk2(b.z, b.w);
    return r.v;
}

__device__ __forceinline__ float2 ubf2(unsigned u) {
    return make_float2(__uint_as_float(u << 16),
                       __uint_as_float(u & 0xffff0000u));
}

__device__ __forceinline__ float bf2f(short s) {
    return __uint_as_float(((unsigned)(unsigned short)s) << 16);
}

// ---------------------------------------------------------------------------
// Fragment-order weight regions (shorts), lane = consuming lane (ml|kg<<4):
//   fragA  [0,199680)        30 tiles x 13 ks x 64 x 8   U(0-9) V(10-19) aW1(20-29)
//   fragP  [199680,250880)   10 tiles x 10 ks x 64 x 8   sc_W1 rows 800..1099
//   fragAt2[250880,276480)   10 tiles x  5 ks x 64 x 8   attn_W2
//   fragW2 [276480,302080)   10 tiles x  5 ks x 64 x 8   sc_W2
// frag[((tile*KS+ks)*64+lane)*8+e] = W[k=ks*32+(lane>>4)*8+e][col=tile*16+(lane&15)]
// ---------------------------------------------------------------------------
__global__ __launch_bounds__(256) void wprep(
    const float* __restrict__ sc_W1, const float* __restrict__ attn_W1,
    const float* __restrict__ attn_W2, const float* __restrict__ sc_W2,
    short* __restrict__ frag)
{
    int t = blockIdx.x * 256 + threadIdx.x;
    if (t >= 302080) return;
    float v = 0.f;
    if (t < 199680) {
        int e = t & 7, g = t >> 3;
        int lane = g & 63, h = g >> 6;
        int ks = h % 13, nt = h / 13;
        int k = ks * 32 + (lane >> 4) * 8 + e;
        int cs = (nt % 10) * 16 + (lane & 15);
        if (k < 400 && cs < HID) {
            if (nt < 10)      v = sc_W1[(long)k * HID + cs];
            else if (nt < 20) v = sc_W1[(long)(400 + k) * HID + cs];
            else              v = attn_W1[(long)k * HID + cs];
        }
    } else if (t < 250880) {
        int r = t - 199680;
        int e = r & 7, g = r >> 3;
        int lane = g & 63, h = g >> 6;
        int ks = h % 10, nt = h / 10;
        int k = ks * 32 + (lane >> 4) * 8 + e;
        int cs = nt * 16 + (lane & 15);
        if (k < 300 && cs < HID) v = sc_W1[(long)(800 + k) * HID + cs];
    } else if (t < 276480) {
        int r = t - 250880;
        int e = r & 7, g = r >> 3;
        int lane = g & 63, h = g >> 6;
        int ks = h % 5, nt = h / 5;
        int k = ks * 32 + (lane >> 4) * 8 + e;
        int cs = nt * 16 + (lane & 15);
        if (k < HID && cs < HID) v = attn_W2[(long)k * HID + cs];
    } else {
        int r = t - 276480;
        int e = r & 7, g = r >> 3;
        int lane = g & 63, h = g >> 6;
        int ks = h % 5, nt = h / 5;
        int k = ks * 32 + (lane >> 4) * 8 + e;
        int cs = nt * 16 + (lane & 15);
        if (k < HID && cs < HID) v = sc_W2[(long)k * HID + cs];
    }
    frag[t] = f2bf(v);
}

// ---------------------------------------------------------------------------
// Batched tile GEMM inner loop (r1-proven): per ks, 1 ds_read_b128 A-fragment
// + NT independent 16B weight loads, then NT MFMAs.
// ---------------------------------------------------------------------------
template<int NT, int KS>
__device__ __forceinline__ void mm_tiles(
    const short* __restrict__ fb,   // frag region base + lane*8
    const short* As,                // LDS A fragments: [(ks*64+lane)*8]
    int w, int lane, f32x4* acc)
{
    #pragma unroll
    for (int ks = 0; ks < KS; ++ks) {
        bf16x8 af = *(const bf16x8*)&As[(ks * 64 + lane) * 8];
        bf16x8 bfr[NT];
        #pragma unroll
        for (int t = 0; t < NT; ++t)
            bfr[t] = *(const bf16x8*)&fb[((4 * t + w) * KS + ks) << 9];
        #pragma unroll
        for (int t = 0; t < NT; ++t)
            acc[t] = __builtin_amdgcn_mfma_f32_16x16x32_bf16(bfr[t], af, acc[t], 0, 0, 0);
    }
}

// ---------------------------------------------------------------------------
// fusedAP (r1 version verbatim — best measured: ~59 us, FETCH ~31 MB).
// 16 rows/block, grid 1250. A staged once in LDS (bf16, fragment layout).
// ---------------------------------------------------------------------------
__global__ __launch_bounds__(256, 4) void fusedAP(
    const float* __restrict__ states, const float* __restrict__ embeds,
    const short* __restrict__ frag,
    const float* __restrict__ scb1, const float* __restrict__ ab1,
    const float* __restrict__ ab2, const float* __restrict__ aW3,
    const float* __restrict__ ab3,
    short* __restrict__ Ubf, short* __restrict__ Vbf, short* __restrict__ Pbf,
    float* __restrict__ logits)
{
    __shared__ short As[13 * 64 * 8];     // 13312 B: A fragments (reused for embeds)
    __shared__ short h1s[16 * 168];
    __shared__ float red[16][4];
    __shared__ float sb1[160], ab1s[160];
    const int tid = threadIdx.x;
    const int w = tid >> 6, lane = tid & 63;
    const int ml = lane & 15, kg = lane >> 4;
    const int m0 = blockIdx.x * 16;          // 1250 * 16 = 20000 exact

    for (int t = tid; t < 160; t += 256) {
        sb1[t]  = (t < HID) ? scb1[t] : 0.f;
        ab1s[t] = (t < HID) ? ab1[t]  : 0.f;
    }
    for (int g = tid; g < 13 * 64; g += 256) {
        int ks = g >> 6, l2 = g & 63;
        int k = ks * 32 + ((l2 >> 4) << 3);
        const float* Ar = states + (long)(m0 + (l2 & 15)) * 400;
        float4 a0 = make_float4(0.f, 0.f, 0.f, 0.f), a1 = a0;
        if (k + 4 <= 400) a0 = *(const float4*)&Ar[k];
        if (k + 8 <= 400) a1 = *(const float4*)&Ar[k + 4];
        *(bf16x8*)&As[g * 8] = cvt8(a0, a1);
    }
    __syncthreads();

    // ---------------- Phase A: states @ {U,V,aW1} ----------------
    f32x4 acc[8];
    #pragma unroll
    for (int t = 0; t < 8; ++t) acc[t] = (f32x4){0.f, 0.f, 0.f, 0.f};
    const short* fb = frag + lane * 8;
    if (w < 2) mm_tiles<8, 13>(fb, As, w, lane, acc);
    else       mm_tiles<7, 13>(fb, As, w, lane, acc);

    const int nT = (w < 2) ? 8 : 7;
    #pragma unroll
    for (int t = 0; t < 8; ++t) {
        if (t < nT) {
            int nt = 4 * t + w;
            if (nt < 10) {                    // U (+sc_b1)
                int col0 = nt * 16 + kg * 4;
                float v[4];
                #pragma unroll
                for (int r = 0; r < 4; ++r) {
                    int c = col0 + r;
                    v[r] = (c < HID) ? acc[t][r] + sb1[c] : 0.f;
                }
                *(uint2*)&Ubf[(long)(m0 + ml) * 160 + col0] =
                    make_uint2(pk2(v[0], v[1]), pk2(v[2], v[3]));
            } else if (nt < 20) {             // V
                int col0 = (nt - 10) * 16 + kg * 4;
                float v[4];
                #pragma unroll
                for (int r = 0; r < 4; ++r) {
                    int c = col0 + r;
                    v[r] = (c < HID) ? acc[t][r] : 0.f;
                }
                *(uint2*)&Vbf[(long)(m0 + ml) * 160 + col0] =
                    make_uint2(pk2(v[0], v[1]), pk2(v[2], v[3]));
            } else {                          // X1 -> relu -> bf16 LDS
                int col0 = (nt - 20) * 16 + kg * 4;
                float v[4];
                #pragma unroll
                for (int r = 0; r < 4; ++r) {
                    int c = col0 + r;
                    v[r] = (c < HID) ? fmaxf(acc[t][r] + ab1s[c], 0.f) : 0.f;
                }
                *(uint2*)&h1s[ml * 168 + col0] =
                    make_uint2(pk2(v[0], v[1]), pk2(v[2], v[3]));
            }
        }
    }
    __syncthreads();   // As reads done + h1s complete

    // ---- restage embeds (16 rows x K=300) into As ----
    for (int g = tid; g < 10 * 64; g += 256) {
        int ks = g >> 6, l2 = g & 63;
        int k = ks * 32 + ((l2 >> 4) << 3);
        const float* Er = embeds + (long)(m0 + (l2 & 15)) * 300;
        float4 a0 = make_float4(0.f, 0.f, 0.f, 0.f), a1 = a0;
        if (k + 4 <= 300) a0 = *(const float4*)&Er[k];
        if (k + 8 <= 300) a1 = *(const float4*)&Er[k + 4];
        *(bf16x8*)&As[g * 8] = cvt8(a0, a1);
    }
    __syncthreads();

    // ---------------- Phase B: embeds @ P-slice ----------------
    {
        f32x4 accP[3];
        #pragma unroll
        for (int t = 0; t < 3; ++t) accP[t] = (f32x4){0.f, 0.f, 0.f, 0.f};
        const short* fP = frag + 199680 + lane * 8;
        if (w < 2) mm_tiles<3, 10>(fP, As, w, lane, accP);
        else       mm_tiles<2, 10>(fP, As, w, lane, accP);

        const int nTp = (w < 2) ? 3 : 2;
        #pragma unroll
        for (int t = 0; t < 3; ++t) {
            if (t < nTp) {
                int nt = 4 * t + w;
                int col0 = nt * 16 + kg * 4;
                float v[4];
                #pragma unroll
                for (int r = 0; r < 4; ++r) {
                    int c = col0 + r;
                    v[r] = (c < HID) ? accP[t][r] : 0.f;
                }
                *(uint2*)&Pbf[(long)(m0 + ml) * 160 + col0] =
                    make_uint2(pk2(v[0], v[1]), pk2(v[2], v[3]));
            }
        }
    }

    // ---------------- Phase C: attn layers 2+3 ----------------
    const short* fAt2 = frag + 250880 + lane * 8;
    bf16x8 af2[5];
    #pragma unroll
    for (int ks = 0; ks < 5; ++ks)
        af2[ks] = *(const bf16x8*)&h1s[ml * 168 + ks * 32 + kg * 8];

    const int nT2 = (w < 2) ? 3 : 2;
    float score[4] = {0.f, 0.f, 0.f, 0.f};
    #pragma unroll
    for (int t = 0; t < 3; ++t) {
        if (t < nT2) {
            int nt = 4 * t + w;
            bf16x8 wb[5];
            #pragma unroll
            for (int ks = 0; ks < 5; ++ks)
                wb[ks] = *(const bf16x8*)&fAt2[(nt * 5 + ks) << 9];
            f32x4 a2 = {0.f, 0.f, 0.f, 0.f};
            #pragma unroll
            for (int ks = 0; ks < 5; ++ks)
                a2 = __builtin_amdgcn_mfma_f32_16x16x32_bf16(af2[ks], wb[ks], a2, 0, 0, 0);
            int col = nt * 16 + ml;
            float b2v = (col < HID) ? ab2[col] : 0.f;
            float w3v = (col < HID) ? aW3[col] : 0.f;
            #pragma unroll
            for (int r = 0; r < 4; ++r)
                score[r] += fmaxf(a2[r] + b2v, 0.f) * w3v;
        }
    }
    #pragma unroll
    for (int r = 0; r < 4; ++r) {
        score[r] += __shfl_xor(score[r], 1);
        score[r] += __shfl_xor(score[r], 2);
        score[r] += __shfl_xor(score[r], 4);
        score[r] += __shfl_xor(score[r], 8);
    }
    if (ml == 0) {
        #pragma unroll
        for (int r = 0; r < 4; ++r) red[kg * 4 + r][w] = score[r];
    }
    __syncthreads();
    if (tid < 16)
        logits[m0 + tid] = red[tid][0] + red[tid][1] + red[tid][2] + red[tid][3] + ab3[0];
}

// ---------------------------------------------------------------------------
// span_all v7 — PREFIX-SUM pooling, barrier-free width-parallel main loop.
// Block = 16 spans (grid 1250, 256 thr). With chunk-local max M:
//   E[t] = sum_{j<t} e_j,  C[t][d] = sum_{j<t} e_j*P[j][d]
//   pooled(i,n) = (C[i+n]-C[i]) / (E[i+n]-E[i])     — O(1) per (span,width)!
// So all 10 widths are independent: wave w owns n in {1-3|4-6|7-8|9-10},
// computes its h1 fragments IN REGISTERS (U,V direct from global L2, C from
// LDS), runs 10x5 MFMAs, reduces, writes out. 2 barriers total (was 10+).
// Cs stored transposed [160][29] f32: odd stride -> conflict-free b32 reads.
// ---------------------------------------------------------------------------
__global__ __launch_bounds__(256) void span_all(
    const short* __restrict__ Ubf, const short* __restrict__ Vbf,
    const short* __restrict__ Pbf, const float* __restrict__ logits,
    const short* __restrict__ fW2, const float* __restrict__ b2,
    const float* __restrict__ W3, const float* __restrict__ b3,
    float* __restrict__ out)
{
    __shared__ float Cs[160][29];   // 18,560 B: prefix of e*P, transposed
    __shared__ float Es[32];        // prefix of e (0..25 used)
    __shared__ float Ls[32];        // raw logits (0..24 used)
    __shared__ float b2s[160], W3s[160];

    const int tid = threadIdx.x;
    const int s0 = blockIdx.x * 16;           // 1250 * 16 = 20000 exact

    if (tid < 32) {
        int r = s0 + tid; if (r > T_LEN - 1) r = T_LEN - 1;
        Ls[tid] = (tid < 25) ? logits[r] : -1e30f;
    }
    for (int t = tid; t < 160; t += 256) {
        b2s[t] = (t < HID) ? b2[t] : 0.f;
        W3s[t] = (t < HID) ? W3[t] : 0.f;
    }
    __syncthreads();

    // ---- prefix scans (threads 0..159: C; thread 160: E) ----
    if (tid < 160) {
        float M = -1e30f;
        #pragma unroll
        for (int t = 0; t < 25; ++t) M = fmaxf(M, Ls[t]);
        float c = 0.f;
        Cs[tid][0] = 0.f;
        #pragma unroll
        for (int t = 0; t < 25; ++t) {
            int r = s0 + t; if (r > T_LEN - 1) r = T_LEN - 1;
            float e = expf(Ls[t] - M);
            c += e * bf2f(Pbf[(long)r * 160 + tid]);
            Cs[tid][t + 1] = c;
        }
    } else if (tid == 160) {
        float M = -1e30f;
        #pragma unroll
        for (int t = 0; t < 25; ++t) M = fmaxf(M, Ls[t]);
        float Ea = 0.f;
        Es[0] = 0.f;
        #pragma unroll
        for (int t = 0; t < 25; ++t) { Ea += expf(Ls[t] - M); Es[t + 1] = Ea; }
    }
    __syncthreads();

    // ---- barrier-free main: wave w owns widths {1-3|4-6|7-8|9-10} ----
    const int w = tid >> 6, lane = tid & 63;
    const int ml = lane & 15, kg = lane >> 4;
    const int i = ml;                         // span row 0..15
    const int sr = s0 + i;
    const int sru = (sr > T_LEN - 1) ? T_LEN - 1 : sr;
    const float bb = b3[0];
    const int nbeg = (w < 2) ? 3 * w + 1 : 2 * w + 3;   // 1,4,7,9
    const int ncnt = (w < 2) ? 3 : 2;
    const int d0 = kg * 8;

    // hoist U fragments (span-start row, n-independent)
    bf16x8 uf[5];
    {
        const short* Up = Ubf + (long)sru * 160 + d0;
        #pragma unroll
        for (int ks = 0; ks < 5; ++ks)
            uf[ks] = *(const bf16x8*)&Up[ks * 32];
    }
    const float E0 = Es[i];
    const short* fw = fW2 + lane * 8;

    for (int nn = 0; nn < ncnt; ++nn) {
        const int n = nbeg + nn;
        const int j = i + n - 1;              // end row 0..24
        int vr = s0 + j; if (vr > T_LEN - 1) vr = T_LEN - 1;
        const float invd = 1.f / (Es[i + n] - E0);
        const short* Vp = Vbf + (long)vr * 160 + d0;

        bf16x8 af[5];
        #pragma unroll
        for (int ks = 0; ks < 5; ++ks) {
            union { bf16x8 v; unsigned u[4]; } U_, V_, R_;
            U_.v = uf[ks];
            V_.v = *(const bf16x8*)&Vp[ks * 32];
            #pragma unroll
            for (int h = 0; h < 4; ++h) {
                float2 ua = ubf2(U_.u[h]);
                float2 va = ubf2(V_.u[h]);
                int d = d0 + ks * 32 + 2 * h;
                float p0 = (Cs[d][i + n]     - Cs[d][i])     * invd;
                float p1 = (Cs[d + 1][i + n] - Cs[d + 1][i]) * invd;
                float x0 = fmaxf(ua.x + va.x + p0, 0.f);
                float x1 = fmaxf(ua.y + va.y + p1, 0.f);
                R_.u[h] = pk2(x0, x1);
            }
            af[ks] = R_.v;
        }

        float sc[4] = {0.f, 0.f, 0.f, 0.f};
        #pragma unroll
        for (int nt = 0; nt < 10; ++nt) {
            f32x4 a2 = {0.f, 0.f, 0.f, 0.f};
            #pragma unroll
            for (int ks = 0; ks < 5; ++ks) {
                bf16x8 bf = *(const bf16x8*)&fw[(nt * 5 + ks) << 9];
                a2 = __builtin_amdgcn_mfma_f32_16x16x32_bf16(af[ks], bf, a2, 0, 0, 0);
            }
            int col = nt * 16 + ml;
            float b2v = b2s[col], w3v = W3s[col];
            #pragma unroll
            for (int r = 0; r < 4; ++r)
                sc[r] += fmaxf(a2[r] + b2v, 0.f) * w3v;
        }
        #pragma unroll
        for (int r = 0; r < 4; ++r) {
            sc[r] += __shfl_xor(sc[r], 1);
            sc[r] += __shfl_xor(sc[r], 2);
            sc[r] += __shfl_xor(sc[r], 4);
            sc[r] += __shfl_xor(sc[r], 8);
        }
        if (ml == 0) {
            int S = T_LEN - n + 1;
            int off = (n - 1) * (T_LEN + 1) - (n - 1) * n / 2;
            int so = s0 + kg * 4;
            #pragma unroll
            for (int r = 0; r < 4; ++r)
                if (so + r < S) out[off + so + r] = sc[r] + bb;
        }
    }
}

// ---------------------------------------------------------------------------
extern "C" void kernel_launch(void* const* d_in, const int* in_sizes, int n_in,
                              void* d_out, int out_size, void* d_ws, size_t ws_size,
                              hipStream_t stream) {
    const float* embeds  = (const float*)d_in[0];
    const float* states  = (const float*)d_in[1];
    const float* attn_W1 = (const float*)d_in[2];
    const float* attn_b1 = (const float*)d_in[3];
    const float* attn_W2 = (const float*)d_in[4];
    const float* attn_b2 = (const float*)d_in[5];
    const float* attn_W3 = (const float*)d_in[6];
    const float* attn_b3 = (const float*)d_in[7];
    const float* sc_W1   = (const float*)d_in[8];
    const float* sc_b1   = (const float*)d_in[9];
    const float* sc_W2   = (const float*)d_in[10];
    const float* sc_b2   = (const float*)d_in[11];
    const float* sc_W3   = (const float*)d_in[12];
    const float* sc_b3   = (const float*)d_in[13];
    float* out = (float*)d_out;

    short* wsS = (short*)d_ws;
    short* Ubf = wsS;                         // [20000][160] bf16
    short* Vbf = wsS + 3200256;
    short* Pbf = wsS + 6400512;
    short* frag = wsS + 9600768;              // 302,080 shorts
    float* logits = (float*)(wsS + 9902848);  // 20,000 floats

    wprep<<<1180, 256, 0, stream>>>(sc_W1, attn_W1, attn_W2, sc_W2, frag);
    fusedAP<<<1250, 256, 0, stream>>>(states, embeds, frag, sc_b1, attn_b1,
                                      attn_b2, attn_W3, attn_b3,
                                      Ubf, Vbf, Pbf, logits);
    span_all<<<1250, 256, 0, stream>>>(Ubf, Vbf, Pbf, logits,
                                       frag + 276480, sc_b2, sc_W3, sc_b3,
                                       out);
}

// Round 10
// 188.200 us; speedup vs baseline: 1.2213x; 1.2213x over previous
//
#include <hip/hip_runtime.h>
#include <hip/hip_bf16.h>
#include <math.h>

#define T_LEN 20000
#define HID 150

typedef __attribute__((ext_vector_type(8))) __bf16 bf16x8;
typedef __attribute__((ext_vector_type(4))) float f32x4;

__device__ __forceinline__ short f2bf(float f) {
    unsigned u = __float_as_uint(f);
    u = (u + 0x7fff + ((u >> 16) & 1)) >> 16;
    return (short)u;
}

__device__ __forceinline__ unsigned pk2(float a, float b) {
    __hip_bfloat162 h = __float22bfloat162_rn(make_float2(a, b));
    return *(unsigned*)&h;
}

__device__ __forceinline__ bf16x8 cvt8(float4 a, float4 b) {
    union { unsigned u[4]; bf16x8 v; } r;
    r.u[0] = pk2(a.x, a.y);
    r.u[1] = pk2(a.z, a.w);
    r.u[2] = pk2(b.x, b.y);
    r.u[3] = pk2(b.z, b.w);
    return r.v;
}

__device__ __forceinline__ float2 ubf2(unsigned u) {
    return make_float2(__uint_as_float(u << 16),
                       __uint_as_float(u & 0xffff0000u));
}

// ---------------------------------------------------------------------------
// Fragment-order weight regions (shorts), lane = consuming lane (ml|kg<<4):
//   fragA  [0,199680)        30 tiles x 13 ks x 64 x 8   U(0-9) V(10-19) aW1(20-29)
//   fragP  [199680,250880)   10 tiles x 10 ks x 64 x 8   sc_W1 rows 800..1099
//   fragAt2[250880,276480)   10 tiles x  5 ks x 64 x 8   attn_W2
//   fragW2 [276480,302080)   10 tiles x  5 ks x 64 x 8   sc_W2
// frag[((tile*KS+ks)*64+lane)*8+e] = W[k=ks*32+(lane>>4)*8+e][col=tile*16+(lane&15)]
// ---------------------------------------------------------------------------
__global__ __launch_bounds__(256) void wprep(
    const float* __restrict__ sc_W1, const float* __restrict__ attn_W1,
    const float* __restrict__ attn_W2, const float* __restrict__ sc_W2,
    short* __restrict__ frag)
{
    int t = blockIdx.x * 256 + threadIdx.x;
    if (t >= 302080) return;
    float v = 0.f;
    if (t < 199680) {
        int e = t & 7, g = t >> 3;
        int lane = g & 63, h = g >> 6;
        int ks = h % 13, nt = h / 13;
        int k = ks * 32 + (lane >> 4) * 8 + e;
        int cs = (nt % 10) * 16 + (lane & 15);
        if (k < 400 && cs < HID) {
            if (nt < 10)      v = sc_W1[(long)k * HID + cs];
            else if (nt < 20) v = sc_W1[(long)(400 + k) * HID + cs];
            else              v = attn_W1[(long)k * HID + cs];
        }
    } else if (t < 250880) {
        int r = t - 199680;
        int e = r & 7, g = r >> 3;
        int lane = g & 63, h = g >> 6;
        int ks = h % 10, nt = h / 10;
        int k = ks * 32 + (lane >> 4) * 8 + e;
        int cs = nt * 16 + (lane & 15);
        if (k < 300 && cs < HID) v = sc_W1[(long)(800 + k) * HID + cs];
    } else if (t < 276480) {
        int r = t - 250880;
        int e = r & 7, g = r >> 3;
        int lane = g & 63, h = g >> 6;
        int ks = h % 5, nt = h / 5;
        int k = ks * 32 + (lane >> 4) * 8 + e;
        int cs = nt * 16 + (lane & 15);
        if (k < HID && cs < HID) v = attn_W2[(long)k * HID + cs];
    } else {
        int r = t - 276480;
        int e = r & 7, g = r >> 3;
        int lane = g & 63, h = g >> 6;
        int ks = h % 5, nt = h / 5;
        int k = ks * 32 + (lane >> 4) * 8 + e;
        int cs = nt * 16 + (lane & 15);
        if (k < HID && cs < HID) v = sc_W2[(long)k * HID + cs];
    }
    frag[t] = f2bf(v);
}

// ---------------------------------------------------------------------------
// Batched tile GEMM inner loop (r1-proven): per ks, 1 ds_read_b128 A-fragment
// + NT independent 16B weight loads, then NT MFMAs.
// ---------------------------------------------------------------------------
template<int NT, int KS>
__device__ __forceinline__ void mm_tiles(
    const short* __restrict__ fb,   // frag region base + lane*8
    const short* As,                // LDS A fragments: [(ks*64+lane)*8]
    int w, int lane, f32x4* acc)
{
    #pragma unroll
    for (int ks = 0; ks < KS; ++ks) {
        bf16x8 af = *(const bf16x8*)&As[(ks * 64 + lane) * 8];
        bf16x8 bfr[NT];
        #pragma unroll
        for (int t = 0; t < NT; ++t)
            bfr[t] = *(const bf16x8*)&fb[((4 * t + w) * KS + ks) << 9];
        #pragma unroll
        for (int t = 0; t < NT; ++t)
            acc[t] = __builtin_amdgcn_mfma_f32_16x16x32_bf16(bfr[t], af, acc[t], 0, 0, 0);
    }
}

// ---------------------------------------------------------------------------
// fusedAP v9: r1's v2 (best measured: ~59 us) with the tail reordered:
//   A -> sync -> {embeds restage || Phase C(attn2/3)} -> sync -> {B || logits}
// One barrier fewer; embeds HBM stage hidden under Phase C's MFMAs.
// ---------------------------------------------------------------------------
__global__ __launch_bounds__(256, 4) void fusedAP(
    const float* __restrict__ states, const float* __restrict__ embeds,
    const short* __restrict__ frag,
    const float* __restrict__ scb1, const float* __restrict__ ab1,
    const float* __restrict__ ab2, const float* __restrict__ aW3,
    const float* __restrict__ ab3,
    short* __restrict__ Ubf, short* __restrict__ Vbf, short* __restrict__ Pbf,
    float* __restrict__ logits)
{
    __shared__ short As[13 * 64 * 8];     // 13312 B: A fragments (reused for embeds)
    __shared__ short h1s[16 * 168];
    __shared__ float red[16][4];
    __shared__ float sb1[160], ab1s[160];
    const int tid = threadIdx.x;
    const int w = tid >> 6, lane = tid & 63;
    const int ml = lane & 15, kg = lane >> 4;
    const int m0 = blockIdx.x * 16;          // 1250 * 16 = 20000 exact

    for (int t = tid; t < 160; t += 256) {
        sb1[t]  = (t < HID) ? scb1[t] : 0.f;
        ab1s[t] = (t < HID) ? ab1[t]  : 0.f;
    }
    // ---- stage states (16 rows x K=400) into As, fragment layout ----
    for (int g = tid; g < 13 * 64; g += 256) {
        int ks = g >> 6, l2 = g & 63;
        int k = ks * 32 + ((l2 >> 4) << 3);
        const float* Ar = states + (long)(m0 + (l2 & 15)) * 400;
        float4 a0 = make_float4(0.f, 0.f, 0.f, 0.f), a1 = a0;
        if (k + 4 <= 400) a0 = *(const float4*)&Ar[k];
        if (k + 8 <= 400) a1 = *(const float4*)&Ar[k + 4];
        *(bf16x8*)&As[g * 8] = cvt8(a0, a1);
    }
    __syncthreads();

    // ---------------- Phase A: states @ {U,V,aW1} ----------------
    f32x4 acc[8];
    #pragma unroll
    for (int t = 0; t < 8; ++t) acc[t] = (f32x4){0.f, 0.f, 0.f, 0.f};
    const short* fb = frag + lane * 8;
    if (w < 2) mm_tiles<8, 13>(fb, As, w, lane, acc);
    else       mm_tiles<7, 13>(fb, As, w, lane, acc);

    const int nT = (w < 2) ? 8 : 7;
    #pragma unroll
    for (int t = 0; t < 8; ++t) {
        if (t < nT) {
            int nt = 4 * t + w;
            if (nt < 10) {                    // U (+sc_b1)
                int col0 = nt * 16 + kg * 4;
                float v[4];
                #pragma unroll
                for (int r = 0; r < 4; ++r) {
                    int c = col0 + r;
                    v[r] = (c < HID) ? acc[t][r] + sb1[c] : 0.f;
                }
                *(uint2*)&Ubf[(long)(m0 + ml) * 160 + col0] =
                    make_uint2(pk2(v[0], v[1]), pk2(v[2], v[3]));
            } else if (nt < 20) {             // V
                int col0 = (nt - 10) * 16 + kg * 4;
                float v[4];
                #pragma unroll
                for (int r = 0; r < 4; ++r) {
                    int c = col0 + r;
                    v[r] = (c < HID) ? acc[t][r] : 0.f;
                }
                *(uint2*)&Vbf[(long)(m0 + ml) * 160 + col0] =
                    make_uint2(pk2(v[0], v[1]), pk2(v[2], v[3]));
            } else {                          // X1 -> relu -> bf16 LDS
                int col0 = (nt - 20) * 16 + kg * 4;
                float v[4];
                #pragma unroll
                for (int r = 0; r < 4; ++r) {
                    int c = col0 + r;
                    v[r] = (c < HID) ? fmaxf(acc[t][r] + ab1s[c], 0.f) : 0.f;
                }
                *(uint2*)&h1s[ml * 168 + col0] =
                    make_uint2(pk2(v[0], v[1]), pk2(v[2], v[3]));
            }
        }
    }
    __syncthreads();   // As reads done + h1s complete

    // ---- restage embeds (16 rows x K=300) into As: issued HERE so the
    //      HBM latency hides under Phase C's attn MFMAs (no As dependency) --
    for (int g = tid; g < 10 * 64; g += 256) {
        int ks = g >> 6, l2 = g & 63;
        int k = ks * 32 + ((l2 >> 4) << 3);
        const float* Er = embeds + (long)(m0 + (l2 & 15)) * 300;
        float4 a0 = make_float4(0.f, 0.f, 0.f, 0.f), a1 = a0;
        if (k + 4 <= 300) a0 = *(const float4*)&Er[k];
        if (k + 8 <= 300) a1 = *(const float4*)&Er[k + 4];
        *(bf16x8*)&As[g * 8] = cvt8(a0, a1);
    }

    // ---------------- Phase C: attn layers 2+3 (h1s + fragAt2 only) --------
    const int nT2 = (w < 2) ? 3 : 2;
    {
        const short* fAt2 = frag + 250880 + lane * 8;
        bf16x8 af2[5];
        #pragma unroll
        for (int ks = 0; ks < 5; ++ks)
            af2[ks] = *(const bf16x8*)&h1s[ml * 168 + ks * 32 + kg * 8];

        float score[4] = {0.f, 0.f, 0.f, 0.f};
        #pragma unroll
        for (int t = 0; t < 3; ++t) {
            if (t < nT2) {
                int nt = 4 * t + w;
                bf16x8 wb[5];
                #pragma unroll
                for (int ks = 0; ks < 5; ++ks)
                    wb[ks] = *(const bf16x8*)&fAt2[(nt * 5 + ks) << 9];
                f32x4 a2 = {0.f, 0.f, 0.f, 0.f};
                #pragma unroll
                for (int ks = 0; ks < 5; ++ks)
                    a2 = __builtin_amdgcn_mfma_f32_16x16x32_bf16(af2[ks], wb[ks], a2, 0, 0, 0);
                int col = nt * 16 + ml;
                float b2v = (col < HID) ? ab2[col] : 0.f;
                float w3v = (col < HID) ? aW3[col] : 0.f;
                #pragma unroll
                for (int r = 0; r < 4; ++r)
                    score[r] += fmaxf(a2[r] + b2v, 0.f) * w3v;
            }
        }
        #pragma unroll
        for (int r = 0; r < 4; ++r) {
            score[r] += __shfl_xor(score[r], 1);
            score[r] += __shfl_xor(score[r], 2);
            score[r] += __shfl_xor(score[r], 4);
            score[r] += __shfl_xor(score[r], 8);
        }
        if (ml == 0) {
            #pragma unroll
            for (int r = 0; r < 4; ++r) red[kg * 4 + r][w] = score[r];
        }
    }
    __syncthreads();   // As (embeds) staged + red complete

    // ---------------- Phase B: embeds @ P-slice ----------------
    {
        f32x4 accP[3];
        #pragma unroll
        for (int t = 0; t < 3; ++t) accP[t] = (f32x4){0.f, 0.f, 0.f, 0.f};
        const short* fP = frag + 199680 + lane * 8;
        if (w < 2) mm_tiles<3, 10>(fP, As, w, lane, accP);
        else       mm_tiles<2, 10>(fP, As, w, lane, accP);

        const int nTp = (w < 2) ? 3 : 2;
        #pragma unroll
        for (int t = 0; t < 3; ++t) {
            if (t < nTp) {
                int nt = 4 * t + w;
                int col0 = nt * 16 + kg * 4;
                float v[4];
                #pragma unroll
                for (int r = 0; r < 4; ++r) {
                    int c = col0 + r;
                    v[r] = (c < HID) ? accP[t][r] : 0.f;
                }
                *(uint2*)&Pbf[(long)(m0 + ml) * 160 + col0] =
                    make_uint2(pk2(v[0], v[1]), pk2(v[2], v[3]));
            }
        }
    }

    if (tid < 16)
        logits[m0 + tid] = red[tid][0] + red[tid][1] + red[tid][2] + red[tid][3] + ab3[0];
}

// ---------------------------------------------------------------------------
// span_all: r0 version verbatim (best measured ~47-53 us). Grid (625, 2).
// Block (x,y): 32 spans of chunk x, widths n in {1..5} (y=0) or {6..10}
// (y=1, 5-row L2-hit prefix). Double-buffered h1s/red, phase1(n+1) overlaps
// phase2(n), ONE sync per n.
// ---------------------------------------------------------------------------
__global__ __launch_bounds__(256) void span_all(
    const short* __restrict__ Ubf, const short* __restrict__ Vbf,
    const short* __restrict__ Pbf, const float* __restrict__ logits,
    const short* __restrict__ fW2, const float* __restrict__ b2,
    const float* __restrict__ W3, const float* __restrict__ b3,
    float* __restrict__ out)
{
    __shared__ short h1s[2][32 * 168];
    __shared__ float red[2][32][2];
    __shared__ float Ls[48], ebuf[48];
    __shared__ float b2s[160], W3s[160];

    const int tid = threadIdx.x;
    const int s0 = blockIdx.x * 32;
    const int nlo = blockIdx.y ? 6 : 1;
    const int nhi = blockIdx.y ? 10 : 5;

    if (tid < 48) {
        int r = s0 + tid; if (r > T_LEN - 1) r = T_LEN - 1;
        Ls[tid] = (tid < 41) ? logits[r] : -1e30f;
    }
    for (int t = tid; t < 160; t += 256) {
        b2s[t] = (t < HID) ? b2[t] : 0.f;
        W3s[t] = (t < HID) ? W3[t] : 0.f;
    }
    __syncthreads();
    if (tid < 48) {
        float M = -1e30f;
        for (int t = 0; t < 41; ++t) M = fmaxf(M, Ls[t]);
        ebuf[tid] = (tid < 41) ? expf(Ls[tid] - M) : 0.f;
    }
    __syncthreads();

    const int i = tid >> 3;       // span 0..31
    const int q = tid & 7;        // dim block [20q, 20q+20)
    const int d0 = 20 * q;
    const int s = s0 + i;
    int su = s; if (su > T_LEN - 1) su = T_LEN - 1;

    float Ur[20];
    {
        const uint2* U2 = (const uint2*)&Ubf[(long)su * 160 + d0];
        #pragma unroll
        for (int c = 0; c < 5; ++c) {
            uint2 uv = U2[c];
            float2 a = ubf2(uv.x), b_ = ubf2(uv.y);
            Ur[4 * c + 0] = a.x;  Ur[4 * c + 1] = a.y;
            Ur[4 * c + 2] = b_.x; Ur[4 * c + 3] = b_.y;
        }
    }
    float accp[20];
    #pragma unroll
    for (int d = 0; d < 20; ++d) accp[d] = 0.f;
    float den = 0.f;

    // prefix j = 0..nlo-2 (only y=1: 5 rows, L2-hit)
    for (int j = 0; j < nlo - 1; ++j) {
        int rr_ = s + j; if (rr_ > T_LEN - 1) rr_ = T_LEN - 1;
        float e = ebuf[i + j];
        den += e;
        const uint2* P2 = (const uint2*)&Pbf[(long)rr_ * 160 + d0];
        #pragma unroll
        for (int c = 0; c < 5; ++c) {
            uint2 pv = P2[c];
            float2 a = ubf2(pv.x), b_ = ubf2(pv.y);
            accp[4 * c + 0] += e * a.x;  accp[4 * c + 1] += e * a.y;
            accp[4 * c + 2] += e * b_.x; accp[4 * c + 3] += e * b_.y;
        }
    }

    const int w = tid >> 6, lane = tid & 63;
    const int ml = lane & 15, kg = lane >> 4;
    const int mt = w >> 1;            // m-tile (spans mt*16..+15)
    const int nt0 = (w & 1) * 5;      // nt half
    const float bb = b3[0];

    // phase1 for n: update accp/den, write h1 -> h1s[p]
    auto phase1 = [&](int n, int p) {
        int rr_ = s + n - 1; if (rr_ > T_LEN - 1) rr_ = T_LEN - 1;
        float e = ebuf[i + n - 1];
        den += e;
        {
            const uint2* P2 = (const uint2*)&Pbf[(long)rr_ * 160 + d0];
            #pragma unroll
            for (int c = 0; c < 5; ++c) {
                uint2 pv = P2[c];
                float2 a = ubf2(pv.x), b_ = ubf2(pv.y);
                accp[4 * c + 0] += e * a.x;  accp[4 * c + 1] += e * a.y;
                accp[4 * c + 2] += e * b_.x; accp[4 * c + 3] += e * b_.y;
            }
        }
        float invd = 1.f / den;
        {
            const uint2* V2 = (const uint2*)&Vbf[(long)rr_ * 160 + d0];
            #pragma unroll
            for (int c = 0; c < 5; ++c) {
                uint2 vv = V2[c];
                float2 a = ubf2(vv.x), b_ = ubf2(vv.y);
                float x0 = fmaxf(Ur[4 * c + 0] + a.x  + accp[4 * c + 0] * invd, 0.f);
                float x1 = fmaxf(Ur[4 * c + 1] + a.y  + accp[4 * c + 1] * invd, 0.f);
                float x2 = fmaxf(Ur[4 * c + 2] + b_.x + accp[4 * c + 2] * invd, 0.f);
                float x3 = fmaxf(Ur[4 * c + 3] + b_.y + accp[4 * c + 3] * invd, 0.f);
                *(uint2*)&h1s[p][i * 168 + d0 + 4 * c] =
                    make_uint2(pk2(x0, x1), pk2(x2, x3));
            }
        }
    };

    phase1(nlo, 0);
    __syncthreads();

    for (int n = nlo; n <= nhi; ++n) {
        const int p = (n - nlo) & 1;
        // phase 1 for n+1 into the other buffer (overlaps phase 2's MFMAs)
        if (n < nhi) phase1(n + 1, 1 - p);

        // phase 2 on h1s[p]
        bf16x8 af[5];
        #pragma unroll
        for (int ks = 0; ks < 5; ++ks)
            af[ks] = *(const bf16x8*)&h1s[p][(mt * 16 + ml) * 168 + ks * 32 + kg * 8];

        float sc[4] = {0.f, 0.f, 0.f, 0.f};
        #pragma unroll
        for (int j = 0; j < 5; ++j) {
            int nt = nt0 + j;
            f32x4 a2 = {0.f, 0.f, 0.f, 0.f};
            #pragma unroll
            for (int ks = 0; ks < 5; ++ks) {
                bf16x8 bf = *(const bf16x8*)&fW2[(long)(((nt * 5 + ks) << 6) | lane) << 3];
                a2 = __builtin_amdgcn_mfma_f32_16x16x32_bf16(af[ks], bf, a2, 0, 0, 0);
            }
            int col = nt * 16 + ml;
            float b2v = b2s[col], w3v = W3s[col];
            #pragma unroll
            for (int r = 0; r < 4; ++r)
                sc[r] += fmaxf(a2[r] + b2v, 0.f) * w3v;
        }
        #pragma unroll
        for (int r = 0; r < 4; ++r) {
            sc[r] += __shfl_xor(sc[r], 1);
            sc[r] += __shfl_xor(sc[r], 2);
            sc[r] += __shfl_xor(sc[r], 4);
            sc[r] += __shfl_xor(sc[r], 8);
        }
        if (ml == 0) {
            #pragma unroll
            for (int r = 0; r < 4; ++r)
                red[p][mt * 16 + kg * 4 + r][w & 1] = sc[r];
        }
        __syncthreads();
        if (tid < 32) {
            int S = T_LEN - n + 1;
            int off = (n - 1) * (T_LEN + 1) - (n - 1) * n / 2;
            int sr = s0 + tid;
            if (sr < S) out[off + sr] = red[p][tid][0] + red[p][tid][1] + bb;
        }
    }
}

// ---------------------------------------------------------------------------
extern "C" void kernel_launch(void* const* d_in, const int* in_sizes, int n_in,
                              void* d_out, int out_size, void* d_ws, size_t ws_size,
                              hipStream_t stream) {
    const float* embeds  = (const float*)d_in[0];
    const float* states  = (const float*)d_in[1];
    const float* attn_W1 = (const float*)d_in[2];
    const float* attn_b1 = (const float*)d_in[3];
    const float* attn_W2 = (const float*)d_in[4];
    const float* attn_b2 = (const float*)d_in[5];
    const float* attn_W3 = (const float*)d_in[6];
    const float* attn_b3 = (const float*)d_in[7];
    const float* sc_W1   = (const float*)d_in[8];
    const float* sc_b1   = (const float*)d_in[9];
    const float* sc_W2   = (const float*)d_in[10];
    const float* sc_b2   = (const float*)d_in[11];
    const float* sc_W3   = (const float*)d_in[12];
    const float* sc_b3   = (const float*)d_in[13];
    float* out = (float*)d_out;

    short* wsS = (short*)d_ws;
    short* Ubf = wsS;                         // [20000][160] bf16
    short* Vbf = wsS + 3200256;
    short* Pbf = wsS + 6400512;
    short* frag = wsS + 9600768;              // 302,080 shorts
    float* logits = (float*)(wsS + 9902848);  // 20,000 floats

    wprep<<<1180, 256, 0, stream>>>(sc_W1, attn_W1, attn_W2, sc_W2, frag);
    fusedAP<<<1250, 256, 0, stream>>>(states, embeds, frag, sc_b1, attn_b1,
                                      attn_b2, attn_W3, attn_b3,
                                      Ubf, Vbf, Pbf, logits);
    span_all<<<dim3(625, 2), 256, 0, stream>>>(Ubf, Vbf, Pbf, logits,
                                               frag + 276480, sc_b2, sc_W3, sc_b3,
                                               out);
}

// Round 11
// 185.375 us; speedup vs baseline: 1.2399x; 1.0152x over previous
//
#include <hip/hip_runtime.h>
#include <hip/hip_bf16.h>
#include <math.h>

#define T_LEN 20000
#define HID 150

typedef __attribute__((ext_vector_type(8))) __bf16 bf16x8;
typedef __attribute__((ext_vector_type(4))) float f32x4;

__device__ __forceinline__ short f2bf(float f) {
    unsigned u = __float_as_uint(f);
    u = (u + 0x7fff + ((u >> 16) & 1)) >> 16;
    return (short)u;
}

__device__ __forceinline__ unsigned pk2(float a, float b) {
    __hip_bfloat162 h = __float22bfloat162_rn(make_float2(a, b));
    return *(unsigned*)&h;
}

__device__ __forceinline__ bf16x8 cvt8(float4 a, float4 b) {
    union { unsigned u[4]; bf16x8 v; } r;
    r.u[0] = pk2(a.x, a.y);
    r.u[1] = pk2(a.z, a.w);
    r.u[2] = pk2(b.x, b.y);
    r.u[3] = pk2(b.z, b.w);
    return r.v;
}

__device__ __forceinline__ float2 ubf2(unsigned u) {
    return make_float2(__uint_as_float(u << 16),
                       __uint_as_float(u & 0xffff0000u));
}

// ---------------------------------------------------------------------------
// Fragment-order weight regions (shorts), lane = consuming lane (ml|kg<<4):
//   fragA  [0,199680)        30 tiles x 13 ks x 64 x 8   U(0-9) V(10-19) aW1(20-29)
//   fragP  [199680,250880)   10 tiles x 10 ks x 64 x 8   sc_W1 rows 800..1099
//   fragAt2[250880,276480)   10 tiles x  5 ks x 64 x 8   attn_W2
//   fragW2 [276480,302080)   10 tiles x  5 ks x 64 x 8   sc_W2
// frag[((tile*KS+ks)*64+lane)*8+e] = W[k=ks*32+(lane>>4)*8+e][col=tile*16+(lane&15)]
// ---------------------------------------------------------------------------
__global__ __launch_bounds__(256) void wprep(
    const float* __restrict__ sc_W1, const float* __restrict__ attn_W1,
    const float* __restrict__ attn_W2, const float* __restrict__ sc_W2,
    short* __restrict__ frag)
{
    int t = blockIdx.x * 256 + threadIdx.x;
    if (t >= 302080) return;
    float v = 0.f;
    if (t < 199680) {
        int e = t & 7, g = t >> 3;
        int lane = g & 63, h = g >> 6;
        int ks = h % 13, nt = h / 13;
        int k = ks * 32 + (lane >> 4) * 8 + e;
        int cs = (nt % 10) * 16 + (lane & 15);
        if (k < 400 && cs < HID) {
            if (nt < 10)      v = sc_W1[(long)k * HID + cs];
            else if (nt < 20) v = sc_W1[(long)(400 + k) * HID + cs];
            else              v = attn_W1[(long)k * HID + cs];
        }
    } else if (t < 250880) {
        int r = t - 199680;
        int e = r & 7, g = r >> 3;
        int lane = g & 63, h = g >> 6;
        int ks = h % 10, nt = h / 10;
        int k = ks * 32 + (lane >> 4) * 8 + e;
        int cs = nt * 16 + (lane & 15);
        if (k < 300 && cs < HID) v = sc_W1[(long)(800 + k) * HID + cs];
    } else if (t < 276480) {
        int r = t - 250880;
        int e = r & 7, g = r >> 3;
        int lane = g & 63, h = g >> 6;
        int ks = h % 5, nt = h / 5;
        int k = ks * 32 + (lane >> 4) * 8 + e;
        int cs = nt * 16 + (lane & 15);
        if (k < HID && cs < HID) v = attn_W2[(long)k * HID + cs];
    } else {
        int r = t - 276480;
        int e = r & 7, g = r >> 3;
        int lane = g & 63, h = g >> 6;
        int ks = h % 5, nt = h / 5;
        int k = ks * 32 + (lane >> 4) * 8 + e;
        int cs = nt * 16 + (lane & 15);
        if (k < HID && cs < HID) v = sc_W2[(long)k * HID + cs];
    }
    frag[t] = f2bf(v);
}

// ---------------------------------------------------------------------------
// synchronous A-chunk staging (16 rows x K) into fragment layout, 512 threads
// ---------------------------------------------------------------------------
template<int KS, int K>
__device__ __forceinline__ void stage_sync(const float* __restrict__ src,
                                           int m0, int tid, short* As)
{
    for (int idx = tid; idx < KS * 64; idx += 512) {
        int ks = idx >> 6, l2 = idx & 63;
        int k = ks * 32 + ((l2 >> 4) << 3);
        const float* Ar = src + (long)(m0 + (l2 & 15)) * K;
        float4 a0 = make_float4(0.f, 0.f, 0.f, 0.f), a1 = a0;
        if (k + 4 <= K) a0 = *(const float4*)&Ar[k];
        if (k + 8 <= K) a1 = *(const float4*)&Ar[k + 4];
        *(bf16x8*)&As[idx * 8] = cvt8(a0, a1);
    }
}

// ---------------------------------------------------------------------------
// fusedT: TILE-RESIDENT weights + grid-stride over row-chunks.
// Grid (250, 3), 512 threads (8 waves); each block does 5 chunks of 16 rows.
//   y=0: fragA tiles 0-15  (U 0-9, V 10-15), wave w owns tiles {2w, 2w+1}
//   y=1: fragA tiles 16-29 (V 16-19, X1 20-29) + attn2/3 + logits
//   y=2: fragP tiles 0-9   (P)
// Weights live in VGPRs for the whole kernel (26 frag loads/lane instead of
// ~134 per chunk) -> the K-loop is pure ds_read+MFMA. A-chunk staging is
// async-split: issue next chunk's global loads BEFORE compute, commit the
// LDS writes after the consume barrier (T14).
// ---------------------------------------------------------------------------
__global__ __launch_bounds__(512) void fusedT(
    const float* __restrict__ states, const float* __restrict__ embeds,
    const short* __restrict__ frag,
    const float* __restrict__ scb1, const float* __restrict__ ab1,
    const float* __restrict__ ab2, const float* __restrict__ aW3,
    const float* __restrict__ ab3,
    short* __restrict__ Ubf, short* __restrict__ Vbf, short* __restrict__ Pbf,
    float* __restrict__ logits)
{
    __shared__ short As[13 * 64 * 8];    // 13,312 B (13 ks max)
    __shared__ short h1s[16 * 168];      // y=1 only
    __shared__ float red[16][8];
    __shared__ float sb1[160], ab1s[160];

    const int tid = threadIdx.x;
    const int w = tid >> 6, lane = tid & 63;
    const int ml = lane & 15, kg = lane >> 4;

    for (int t = tid; t < 160; t += 512) {
        sb1[t]  = (t < HID) ? scb1[t] : 0.f;
        ab1s[t] = (t < HID) ? ab1[t]  : 0.f;
    }

    if (blockIdx.y == 0) {
        // ============ y=0: tiles 0-15 (U + V-low), states ============
        const int t0 = 2 * w;
        bf16x8 wA[2][13];
        #pragma unroll
        for (int t = 0; t < 2; ++t)
            #pragma unroll
            for (int ks = 0; ks < 13; ++ks)
                wA[t][ks] = *(const bf16x8*)&frag[(((t0 + t) * 13 + ks) << 9) + lane * 8];

        int c = blockIdx.x;
        stage_sync<13, 400>(states, c * 16, tid, As);
        __syncthreads();

        for (; c < 1250; c += 250) {
            const int cn = c + 250;
            float4 qa[2][2];
            #pragma unroll
            for (int it = 0; it < 2; ++it) {
                int idx = tid + (it << 9);
                if (cn < 1250 && idx < 832) {
                    int ks = idx >> 6, l2 = idx & 63;
                    int k = ks * 32 + ((l2 >> 4) << 3);
                    const float* Ar = states + (long)(cn * 16 + (l2 & 15)) * 400;
                    qa[it][0] = (k + 4 <= 400) ? *(const float4*)&Ar[k]     : make_float4(0.f,0.f,0.f,0.f);
                    qa[it][1] = (k + 8 <= 400) ? *(const float4*)&Ar[k + 4] : make_float4(0.f,0.f,0.f,0.f);
                }
            }

            const int m0 = c * 16;
            f32x4 acc[2];
            acc[0] = (f32x4){0.f, 0.f, 0.f, 0.f};
            acc[1] = (f32x4){0.f, 0.f, 0.f, 0.f};
            #pragma unroll
            for (int ks = 0; ks < 13; ++ks) {
                bf16x8 af = *(const bf16x8*)&As[(ks * 64 + lane) * 8];
                acc[0] = __builtin_amdgcn_mfma_f32_16x16x32_bf16(wA[0][ks], af, acc[0], 0, 0, 0);
                acc[1] = __builtin_amdgcn_mfma_f32_16x16x32_bf16(wA[1][ks], af, acc[1], 0, 0, 0);
            }
            #pragma unroll
            for (int t = 0; t < 2; ++t) {
                int nt = t0 + t;
                if (nt < 10) {                    // U (+sc_b1)
                    int col0 = nt * 16 + kg * 4;
                    float v[4];
                    #pragma unroll
                    for (int r = 0; r < 4; ++r) {
                        int cc = col0 + r;
                        v[r] = (cc < HID) ? acc[t][r] + sb1[cc] : 0.f;
                    }
                    *(uint2*)&Ubf[(long)(m0 + ml) * 160 + col0] =
                        make_uint2(pk2(v[0], v[1]), pk2(v[2], v[3]));
                } else {                          // V cols 0..95
                    int col0 = (nt - 10) * 16 + kg * 4;
                    float v[4];
                    #pragma unroll
                    for (int r = 0; r < 4; ++r) {
                        int cc = col0 + r;
                        v[r] = (cc < HID) ? acc[t][r] : 0.f;
                    }
                    *(uint2*)&Vbf[(long)(m0 + ml) * 160 + col0] =
                        make_uint2(pk2(v[0], v[1]), pk2(v[2], v[3]));
                }
            }
            __syncthreads();   // As consumed
            if (cn < 1250) {
                #pragma unroll
                for (int it = 0; it < 2; ++it) {
                    int idx = tid + (it << 9);
                    if (idx < 832) *(bf16x8*)&As[idx * 8] = cvt8(qa[it][0], qa[it][1]);
                }
            }
            __syncthreads();   // As ready
        }
    } else if (blockIdx.y == 1) {
        // ===== y=1: tiles 16-29 (V-high + X1) + attn2/3 + logits, states =====
        const int nTi = (w < 6) ? 2 : 1;
        const int t0 = (w < 6) ? 16 + 2 * w : 28 + (w - 6);
        bf16x8 wA[2][13];
        #pragma unroll
        for (int t = 0; t < 2; ++t)
            if (t < nTi) {
                #pragma unroll
                for (int ks = 0; ks < 13; ++ks)
                    wA[t][ks] = *(const bf16x8*)&frag[(((t0 + t) * 13 + ks) << 9) + lane * 8];
            }
        const int ct0 = (w < 2) ? 2 * w : w + 2;     // attn2 tiles
        const int nC = (w < 2) ? 2 : 1;
        const short* fAt2 = frag + 250880 + lane * 8;

        int c = blockIdx.x;
        stage_sync<13, 400>(states, c * 16, tid, As);
        __syncthreads();

        for (; c < 1250; c += 250) {
            const int cn = c + 250;
            float4 qa[2][2];
            #pragma unroll
            for (int it = 0; it < 2; ++it) {
                int idx = tid + (it << 9);
                if (cn < 1250 && idx < 832) {
                    int ks = idx >> 6, l2 = idx & 63;
                    int k = ks * 32 + ((l2 >> 4) << 3);
                    const float* Ar = states + (long)(cn * 16 + (l2 & 15)) * 400;
                    qa[it][0] = (k + 4 <= 400) ? *(const float4*)&Ar[k]     : make_float4(0.f,0.f,0.f,0.f);
                    qa[it][1] = (k + 8 <= 400) ? *(const float4*)&Ar[k + 4] : make_float4(0.f,0.f,0.f,0.f);
                }
            }

            const int m0 = c * 16;
            f32x4 acc[2];
            acc[0] = (f32x4){0.f, 0.f, 0.f, 0.f};
            acc[1] = (f32x4){0.f, 0.f, 0.f, 0.f};
            #pragma unroll
            for (int ks = 0; ks < 13; ++ks) {
                bf16x8 af = *(const bf16x8*)&As[(ks * 64 + lane) * 8];
                #pragma unroll
                for (int t = 0; t < 2; ++t)
                    if (t < nTi)
                        acc[t] = __builtin_amdgcn_mfma_f32_16x16x32_bf16(wA[t][ks], af, acc[t], 0, 0, 0);
            }
            #pragma unroll
            for (int t = 0; t < 2; ++t) {
                if (t < nTi) {
                    int nt = t0 + t;
                    if (nt < 20) {                // V cols 96..159
                        int col0 = (nt - 10) * 16 + kg * 4;
                        float v[4];
                        #pragma unroll
                        for (int r = 0; r < 4; ++r) {
                            int cc = col0 + r;
                            v[r] = (cc < HID) ? acc[t][r] : 0.f;
                        }
                        *(uint2*)&Vbf[(long)(m0 + ml) * 160 + col0] =
                            make_uint2(pk2(v[0], v[1]), pk2(v[2], v[3]));
                    } else {                      // X1 -> relu -> h1s
                        int col0 = (nt - 20) * 16 + kg * 4;
                        float v[4];
                        #pragma unroll
                        for (int r = 0; r < 4; ++r) {
                            int cc = col0 + r;
                            v[r] = (cc < HID) ? fmaxf(acc[t][r] + ab1s[cc], 0.f) : 0.f;
                        }
                        *(uint2*)&h1s[ml * 168 + col0] =
                            make_uint2(pk2(v[0], v[1]), pk2(v[2], v[3]));
                    }
                }
            }
            __syncthreads();   // h1s complete (As also consumed)

            // ---- attn layers 2+3 ----
            {
                bf16x8 af2[5];
                #pragma unroll
                for (int ks = 0; ks < 5; ++ks)
                    af2[ks] = *(const bf16x8*)&h1s[ml * 168 + ks * 32 + kg * 8];

                float score[4] = {0.f, 0.f, 0.f, 0.f};
                #pragma unroll
                for (int t = 0; t < 2; ++t) {
                    if (t < nC) {
                        int nt = ct0 + t;
                        bf16x8 wb[5];
                        #pragma unroll
                        for (int ks = 0; ks < 5; ++ks)
                            wb[ks] = *(const bf16x8*)&fAt2[(nt * 5 + ks) << 9];
                        f32x4 a2 = {0.f, 0.f, 0.f, 0.f};
                        #pragma unroll
                        for (int ks = 0; ks < 5; ++ks)
                            a2 = __builtin_amdgcn_mfma_f32_16x16x32_bf16(af2[ks], wb[ks], a2, 0, 0, 0);
                        int col = nt * 16 + ml;
                        float b2v = (col < HID) ? ab2[col] : 0.f;
                        float w3v = (col < HID) ? aW3[col] : 0.f;
                        #pragma unroll
                        for (int r = 0; r < 4; ++r)
                            score[r] += fmaxf(a2[r] + b2v, 0.f) * w3v;
                    }
                }
                #pragma unroll
                for (int r = 0; r < 4; ++r) {
                    score[r] += __shfl_xor(score[r], 1);
                    score[r] += __shfl_xor(score[r], 2);
                    score[r] += __shfl_xor(score[r], 4);
                    score[r] += __shfl_xor(score[r], 8);
                }
                if (ml == 0) {
                    #pragma unroll
                    for (int r = 0; r < 4; ++r) red[kg * 4 + r][w] = score[r];
                }
            }
            __syncthreads();   // red complete
            if (tid < 16)
                logits[m0 + tid] = red[tid][0] + red[tid][1] + red[tid][2] + red[tid][3] +
                                   red[tid][4] + red[tid][5] + red[tid][6] + red[tid][7] + ab3[0];

            if (cn < 1250) {
                #pragma unroll
                for (int it = 0; it < 2; ++it) {
                    int idx = tid + (it << 9);
                    if (idx < 832) *(bf16x8*)&As[idx * 8] = cvt8(qa[it][0], qa[it][1]);
                }
            }
            __syncthreads();   // As ready (also guards h1s/red reuse)
        }
    } else {
        // ============ y=2: fragP tiles 0-9 (P), embeds ============
        const int nP = (w < 2) ? 2 : 1;
        const int t0 = (w < 2) ? 2 * w : w + 2;
        bf16x8 wP[2][10];
        #pragma unroll
        for (int t = 0; t < 2; ++t)
            if (t < nP) {
                #pragma unroll
                for (int ks = 0; ks < 10; ++ks)
                    wP[t][ks] = *(const bf16x8*)&frag[199680 + (((t0 + t) * 10 + ks) << 9) + lane * 8];
            }

        int c = blockIdx.x;
        stage_sync<10, 300>(embeds, c * 16, tid, As);
        __syncthreads();

        for (; c < 1250; c += 250) {
            const int cn = c + 250;
            float4 qa[2][2];
            #pragma unroll
            for (int it = 0; it < 2; ++it) {
                int idx = tid + (it << 9);
                if (cn < 1250 && idx < 640) {
                    int ks = idx >> 6, l2 = idx & 63;
                    int k = ks * 32 + ((l2 >> 4) << 3);
                    const float* Ar = embeds + (long)(cn * 16 + (l2 & 15)) * 300;
                    qa[it][0] = (k + 4 <= 300) ? *(const float4*)&Ar[k]     : make_float4(0.f,0.f,0.f,0.f);
                    qa[it][1] = (k + 8 <= 300) ? *(const float4*)&Ar[k + 4] : make_float4(0.f,0.f,0.f,0.f);
                }
            }

            const int m0 = c * 16;
            f32x4 acc[2];
            acc[0] = (f32x4){0.f, 0.f, 0.f, 0.f};
            acc[1] = (f32x4){0.f, 0.f, 0.f, 0.f};
            #pragma unroll
            for (int ks = 0; ks < 10; ++ks) {
                bf16x8 af = *(const bf16x8*)&As[(ks * 64 + lane) * 8];
                #pragma unroll
                for (int t = 0; t < 2; ++t)
                    if (t < nP)
                        acc[t] = __builtin_amdgcn_mfma_f32_16x16x32_bf16(wP[t][ks], af, acc[t], 0, 0, 0);
            }
            #pragma unroll
            for (int t = 0; t < 2; ++t) {
                if (t < nP) {
                    int col0 = (t0 + t) * 16 + kg * 4;
                    float v[4];
                    #pragma unroll
                    for (int r = 0; r < 4; ++r) {
                        int cc = col0 + r;
                        v[r] = (cc < HID) ? acc[t][r] : 0.f;
                    }
                    *(uint2*)&Pbf[(long)(m0 + ml) * 160 + col0] =
                        make_uint2(pk2(v[0], v[1]), pk2(v[2], v[3]));
                }
            }
            __syncthreads();   // As consumed
            if (cn < 1250) {
                #pragma unroll
                for (int it = 0; it < 2; ++it) {
                    int idx = tid + (it << 9);
                    if (idx < 640) *(bf16x8*)&As[idx * 8] = cvt8(qa[it][0], qa[it][1]);
                }
            }
            __syncthreads();   // As ready
        }
    }
}

// ---------------------------------------------------------------------------
// span_all: r0 version verbatim (best measured ~47-53 us). Grid (625, 2).
// ---------------------------------------------------------------------------
__global__ __launch_bounds__(256) void span_all(
    const short* __restrict__ Ubf, const short* __restrict__ Vbf,
    const short* __restrict__ Pbf, const float* __restrict__ logits,
    const short* __restrict__ fW2, const float* __restrict__ b2,
    const float* __restrict__ W3, const float* __restrict__ b3,
    float* __restrict__ out)
{
    __shared__ short h1s[2][32 * 168];
    __shared__ float red[2][32][2];
    __shared__ float Ls[48], ebuf[48];
    __shared__ float b2s[160], W3s[160];

    const int tid = threadIdx.x;
    const int s0 = blockIdx.x * 32;
    const int nlo = blockIdx.y ? 6 : 1;
    const int nhi = blockIdx.y ? 10 : 5;

    if (tid < 48) {
        int r = s0 + tid; if (r > T_LEN - 1) r = T_LEN - 1;
        Ls[tid] = (tid < 41) ? logits[r] : -1e30f;
    }
    for (int t = tid; t < 160; t += 256) {
        b2s[t] = (t < HID) ? b2[t] : 0.f;
        W3s[t] = (t < HID) ? W3[t] : 0.f;
    }
    __syncthreads();
    if (tid < 48) {
        float M = -1e30f;
        for (int t = 0; t < 41; ++t) M = fmaxf(M, Ls[t]);
        ebuf[tid] = (tid < 41) ? expf(Ls[tid] - M) : 0.f;
    }
    __syncthreads();

    const int i = tid >> 3;       // span 0..31
    const int q = tid & 7;        // dim block [20q, 20q+20)
    const int d0 = 20 * q;
    const int s = s0 + i;
    int su = s; if (su > T_LEN - 1) su = T_LEN - 1;

    float Ur[20];
    {
        const uint2* U2 = (const uint2*)&Ubf[(long)su * 160 + d0];
        #pragma unroll
        for (int c = 0; c < 5; ++c) {
            uint2 uv = U2[c];
            float2 a = ubf2(uv.x), b_ = ubf2(uv.y);
            Ur[4 * c + 0] = a.x;  Ur[4 * c + 1] = a.y;
            Ur[4 * c + 2] = b_.x; Ur[4 * c + 3] = b_.y;
        }
    }
    float accp[20];
    #pragma unroll
    for (int d = 0; d < 20; ++d) accp[d] = 0.f;
    float den = 0.f;

    for (int j = 0; j < nlo - 1; ++j) {
        int rr_ = s + j; if (rr_ > T_LEN - 1) rr_ = T_LEN - 1;
        float e = ebuf[i + j];
        den += e;
        const uint2* P2 = (const uint2*)&Pbf[(long)rr_ * 160 + d0];
        #pragma unroll
        for (int c = 0; c < 5; ++c) {
            uint2 pv = P2[c];
            float2 a = ubf2(pv.x), b_ = ubf2(pv.y);
            accp[4 * c + 0] += e * a.x;  accp[4 * c + 1] += e * a.y;
            accp[4 * c + 2] += e * b_.x; accp[4 * c + 3] += e * b_.y;
        }
    }

    const int w = tid >> 6, lane = tid & 63;
    const int ml = lane & 15, kg = lane >> 4;
    const int mt = w >> 1;
    const int nt0 = (w & 1) * 5;
    const float bb = b3[0];

    auto phase1 = [&](int n, int p) {
        int rr_ = s + n - 1; if (rr_ > T_LEN - 1) rr_ = T_LEN - 1;
        float e = ebuf[i + n - 1];
        den += e;
        {
            const uint2* P2 = (const uint2*)&Pbf[(long)rr_ * 160 + d0];
            #pragma unroll
            for (int c = 0; c < 5; ++c) {
                uint2 pv = P2[c];
                float2 a = ubf2(pv.x), b_ = ubf2(pv.y);
                accp[4 * c + 0] += e * a.x;  accp[4 * c + 1] += e * a.y;
                accp[4 * c + 2] += e * b_.x; accp[4 * c + 3] += e * b_.y;
            }
        }
        float invd = 1.f / den;
        {
            const uint2* V2 = (const uint2*)&Vbf[(long)rr_ * 160 + d0];
            #pragma unroll
            for (int c = 0; c < 5; ++c) {
                uint2 vv = V2[c];
                float2 a = ubf2(vv.x), b_ = ubf2(vv.y);
                float x0 = fmaxf(Ur[4 * c + 0] + a.x  + accp[4 * c + 0] * invd, 0.f);
                float x1 = fmaxf(Ur[4 * c + 1] + a.y  + accp[4 * c + 1] * invd, 0.f);
                float x2 = fmaxf(Ur[4 * c + 2] + b_.x + accp[4 * c + 2] * invd, 0.f);
                float x3 = fmaxf(Ur[4 * c + 3] + b_.y + accp[4 * c + 3] * invd, 0.f);
                *(uint2*)&h1s[p][i * 168 + d0 + 4 * c] =
                    make_uint2(pk2(x0, x1), pk2(x2, x3));
            }
        }
    };

    phase1(nlo, 0);
    __syncthreads();

    for (int n = nlo; n <= nhi; ++n) {
        const int p = (n - nlo) & 1;
        if (n < nhi) phase1(n + 1, 1 - p);

        bf16x8 af[5];
        #pragma unroll
        for (int ks = 0; ks < 5; ++ks)
            af[ks] = *(const bf16x8*)&h1s[p][(mt * 16 + ml) * 168 + ks * 32 + kg * 8];

        float sc[4] = {0.f, 0.f, 0.f, 0.f};
        #pragma unroll
        for (int j = 0; j < 5; ++j) {
            int nt = nt0 + j;
            f32x4 a2 = {0.f, 0.f, 0.f, 0.f};
            #pragma unroll
            for (int ks = 0; ks < 5; ++ks) {
                bf16x8 bf = *(const bf16x8*)&fW2[(long)(((nt * 5 + ks) << 6) | lane) << 3];
                a2 = __builtin_amdgcn_mfma_f32_16x16x32_bf16(af[ks], bf, a2, 0, 0, 0);
            }
            int col = nt * 16 + ml;
            float b2v = b2s[col], w3v = W3s[col];
            #pragma unroll
            for (int r = 0; r < 4; ++r)
                sc[r] += fmaxf(a2[r] + b2v, 0.f) * w3v;
        }
        #pragma unroll
        for (int r = 0; r < 4; ++r) {
            sc[r] += __shfl_xor(sc[r], 1);
            sc[r] += __shfl_xor(sc[r], 2);
            sc[r] += __shfl_xor(sc[r], 4);
            sc[r] += __shfl_xor(sc[r], 8);
        }
        if (ml == 0) {
            #pragma unroll
            for (int r = 0; r < 4; ++r)
                red[p][mt * 16 + kg * 4 + r][w & 1] = sc[r];
        }
        __syncthreads();
        if (tid < 32) {
            int S = T_LEN - n + 1;
            int off = (n - 1) * (T_LEN + 1) - (n - 1) * n / 2;
            int sr = s0 + tid;
            if (sr < S) out[off + sr] = red[p][tid][0] + red[p][tid][1] + bb;
        }
    }
}

// ---------------------------------------------------------------------------
extern "C" void kernel_launch(void* const* d_in, const int* in_sizes, int n_in,
                              void* d_out, int out_size, void* d_ws, size_t ws_size,
                              hipStream_t stream) {
    const float* embeds  = (const float*)d_in[0];
    const float* states  = (const float*)d_in[1];
    const float* attn_W1 = (const float*)d_in[2];
    const float* attn_b1 = (const float*)d_in[3];
    const float* attn_W2 = (const float*)d_in[4];
    const float* attn_b2 = (const float*)d_in[5];
    const float* attn_W3 = (const float*)d_in[6];
    const float* attn_b3 = (const float*)d_in[7];
    const float* sc_W1   = (const float*)d_in[8];
    const float* sc_b1   = (const float*)d_in[9];
    const float* sc_W2   = (const float*)d_in[10];
    const float* sc_b2   = (const float*)d_in[11];
    const float* sc_W3   = (const float*)d_in[12];
    const float* sc_b3   = (const float*)d_in[13];
    float* out = (float*)d_out;

    short* wsS = (short*)d_ws;
    short* Ubf = wsS;                         // [20000][160] bf16
    short* Vbf = wsS + 3200256;
    short* Pbf = wsS + 6400512;
    short* frag = wsS + 9600768;              // 302,080 shorts
    float* logits = (float*)(wsS + 9902848);  // 20,000 floats

    wprep<<<1180, 256, 0, stream>>>(sc_W1, attn_W1, attn_W2, sc_W2, frag);
    fusedT<<<dim3(250, 3), 512, 0, stream>>>(states, embeds, frag, sc_b1, attn_b1,
                                             attn_b2, attn_W3, attn_b3,
                                             Ubf, Vbf, Pbf, logits);
    span_all<<<dim3(625, 2), 256, 0, stream>>>(Ubf, Vbf, Pbf, logits,
                                               frag + 276480, sc_b2, sc_W3, sc_b3,
                                               out);
}